// Round 9
// baseline (431.831 us; speedup 1.0000x reference)
//
#include <hip/hip_runtime.h>
#include <hip/hip_bf16.h>

#define NCELLS 256
#define DIM    512
#define NTOK   131072

typedef __attribute__((ext_vector_type(8))) short  bf16x8;
typedef __attribute__((ext_vector_type(4))) float  f32x4;
typedef __attribute__((ext_vector_type(4))) short  s16x4;

static __device__ __forceinline__ unsigned short f2bf(float f) {
    union { float f; unsigned u; } v; v.f = f;
    unsigned r = v.u + 0x7fffu + ((v.u >> 16) & 1u);
    return (unsigned short)(r >> 16);
}
static __device__ __forceinline__ float bf2f(unsigned short h) {
    union { unsigned u; float f; } v; v.u = ((unsigned)h) << 16;
    return v.f;
}
static __device__ __forceinline__ bf16x8 cvt8(f32x4 a, f32x4 b) {
    bf16x8 r;
    r[0] = (short)f2bf(a[0]); r[1] = (short)f2bf(a[1]);
    r[2] = (short)f2bf(a[2]); r[3] = (short)f2bf(a[3]);
    r[4] = (short)f2bf(b[0]); r[5] = (short)f2bf(b[1]);
    r[6] = (short)f2bf(b[2]); r[7] = (short)f2bf(b[3]);
    return r;
}

// ---------------- prep: B operands pre-swizzled into MFMA-FRAGMENT order ----------------
// pcombB: phase-2 B. For cell-tile ct (16 cells), mat m (0=proto,1=grid), K-slice s
//   (dims 32s..32s+31): 64 fragment units of 16B; unit (g*16 + r) holds
//   proto/grid[cell ct*16+r][dims 32s+8g .. +7].  A wave (lanes (r,g)) reads units
//   0..63 = one contiguous 1 KB line -> perfectly coalesced global_load_dwordx4.
// protoB: phase-5 B. For dim-tile dt (16 dims), cell-slice s (cells 32s..+31):
//   unit (g*16 + r) holds proto[cells 32s+8g..+7][dim dt*16+r] (transposed gather).
__global__ void __launch_bounds__(256) prep_kernel(
        const float* __restrict__ proto, const float* __restrict__ grid,
        const float* __restrict__ temp_raw, const float* __restrict__ gate_logits,
        unsigned short* __restrict__ pcombB,   // 512 KB
        unsigned short* __restrict__ protoB,   // 256 KB
        float* __restrict__ pp, float* __restrict__ gg,
        float* __restrict__ gate, float* __restrict__ invT)
{
    const int c = blockIdx.x;   // cell 0..255
    const int t = threadIdx.x;  // 0..255
    const int ct = c >> 4, rl = c & 15;
    const int cs = c >> 5, cg = (c >> 3) & 3, ce = c & 7;   // cell decomposed for protoB
    float sp = 0.f, sg = 0.f;
    for (int i = t; i < DIM; i += 256) {
        float pv = proto[c * DIM + i];
        float gv = grid[c * DIM + i];
        const int s = i >> 5, gq = (i >> 3) & 3, e = i & 7;
        const size_t uP = ((size_t)((ct * 2 + 0) * 16 + s) * 64 + gq * 16 + rl) * 8 + e;
        const size_t uG = ((size_t)((ct * 2 + 1) * 16 + s) * 64 + gq * 16 + rl) * 8 + e;
        pcombB[uP] = f2bf(pv);
        pcombB[uG] = f2bf(gv);
        const int dt = i >> 4, rr = i & 15;
        protoB[((size_t)(dt * 8 + cs) * 64 + cg * 16 + rr) * 8 + ce] = f2bf(pv);
        sp += pv * pv; sg += gv * gv;
    }
    for (int m = 1; m < 64; m <<= 1) { sp += __shfl_xor(sp, m); sg += __shfl_xor(sg, m); }
    __shared__ float redp[4], redg[4];
    const int wv = t >> 6;
    if ((t & 63) == 0) { redp[wv] = sp; redg[wv] = sg; }
    __syncthreads();
    if (t == 0) {
        pp[c] = redp[0] + redp[1] + redp[2] + redp[3];
        gg[c] = redg[0] + redg[1] + redg[2] + redg[3];
        gate[c] = 1.f / (1.f + expf(-gate_logits[c]));
        if (c == 0) {
            float T = (1.f / (1.f + expf(-temp_raw[0]))) * (1.f - 0.001f) + 0.001f;
            invT[0] = 1.f / T;
        }
    }
}

// ---------------- main fused kernel — ZERO barriers, zero inline asm ----------------
// 4 waves/block (256 thr), 16 tokens/wave, 64 tokens/block, 2048 blocks.
// B operands are read straight from global (L2-resident, fragment-ordered,
// coalesced 1 KB/wave-instr). No LDS staging => no cross-wave sync at all.
// lds_w is PER-WAVE (same wave writes then reads) -> compiler orders via its own
// lgkmcnt insertion. All latency hiding = compiler vmcnt counting on register
// deps + wave TLP. Rounds 5-8 lesson: hand-managed staging discipline is
// unverifiable here; this design has no discipline to get wrong.
// Numerics/phases identical to the PASSING round-4 kernel.
__global__ void __launch_bounds__(256) som_main(
        const float* __restrict__ x,
        const unsigned short* __restrict__ pcombB,
        const unsigned short* __restrict__ protoB,
        const float* __restrict__ pp, const float* __restrict__ gg,
        const float* __restrict__ gate, const float* __restrict__ invTp,
        float* __restrict__ out_blend, float* __restrict__ out_w)
{
    const int tid  = threadIdx.x;
    const int lane = tid & 63;
    const int wv   = tid >> 6;                   // 0..3
    const int tb   = blockIdx.x * 64 + wv * 16;  // wave's token base
    const int r    = lane & 15;
    const int g    = lane >> 4;
    const int k8   = g * 8;

    __shared__ __align__(16) unsigned short lds_w[4][16][256];  // 32 KB, per-wave only

    const float invT = invTp[0];

    // ---- Phase 1: x tile -> A fragments (bf16) + |x|^2 (fp32) ----
    bf16x8 a1[16];
    float xx_part = 0.f;
    const float* xrow = x + (size_t)(tb + r) * DIM;
    #pragma unroll
    for (int ks = 0; ks < 16; ++ks) {
        const f32x4* p0 = (const f32x4*)(xrow + ks * 32 + k8);
        f32x4 u0 = p0[0], u1 = p0[1];
        #pragma unroll
        for (int i = 0; i < 4; ++i) xx_part += u0[i] * u0[i] + u1[i] * u1[i];
        a1[ks] = cvt8(u0, u1);
    }
    xx_part += __shfl_xor(xx_part, 16);
    xx_part += __shfl_xor(xx_part, 32);
    float xt[4];
    #pragma unroll
    for (int j = 0; j < 4; ++j) xt[j] = __shfl(xx_part, g * 4 + j);

    // ---- Phase 2: 16 cell-tiles; B-fragments direct from global (L2) ----
    // z = 64 - d_total/T (z<=64 since d>=0): exp never overflows, no max pass.
    float s1[4] = {0.f, 0.f, 0.f, 0.f};
    float s2[4] = {0.f, 0.f, 0.f, 0.f};
    const int lo = g * 16 + r;   // this lane's fragment-unit offset
    #pragma unroll 1
    for (int ct = 0; ct < 16; ++ct) {
        const bf16x8* bP = (const bf16x8*)pcombB + (size_t)(ct * 2) * 16 * 64 + lo;
        const bf16x8* bG = bP + 16 * 64;
        f32x4 accP = {0.f, 0.f, 0.f, 0.f};
        f32x4 accG = {0.f, 0.f, 0.f, 0.f};
        #pragma unroll
        for (int s = 0; s < 16; ++s) {
            accP = __builtin_amdgcn_mfma_f32_16x16x32_bf16(a1[s], bP[s * 64], accP, 0, 0, 0);
            accG = __builtin_amdgcn_mfma_f32_16x16x32_bf16(a1[s], bG[s * 64], accG, 0, 0, 0);
        }
        const int cell = ct * 16 + r;
        const float ppc = pp[cell], ggc = gg[cell], gtc = gate[cell];
        #pragma unroll
        for (int j = 0; j < 4; ++j) {
            float dp = sqrtf(fmaxf(xt[j] + ppc - 2.f * accP[j], 0.f));
            float dg = sqrtf(fmaxf(xt[j] + ggc - 2.f * accG[j], 0.f));
            float zj = 64.f - (dp + dg) * invT;
            float ep = __expf(zj);
            float eg = ep * gtc;
            s1[j] += ep;
            s2[j] += eg;
            const int tok = g * 4 + j;
            lds_w[wv][tok][(((ct * 2 + (r >> 3)) ^ (tok & 7)) << 3) + (r & 7)] = f2bf(eg);
        }
    }

    // ---- Phase 3: denominators (reduce within 16-lane group) ----
    float rden[4];
    #pragma unroll
    for (int j = 0; j < 4; ++j) {
        float a = s1[j], b = s2[j];
        a += __shfl_xor(a, 1); b += __shfl_xor(b, 1);
        a += __shfl_xor(a, 2); b += __shfl_xor(b, 2);
        a += __shfl_xor(a, 4); b += __shfl_xor(b, 4);
        a += __shfl_xor(a, 8); b += __shfl_xor(b, 8);
        rden[j] = 1.f / (b + 1e-8f * a);
    }

    // ---- Phase 4: weights out (own wave's lds_w -> full-line dwordx4 stores) ----
    float* wout = out_w + (size_t)tb * NCELLS;
    #pragma unroll
    for (int t0 = 0; t0 < 16; ++t0) {
        float rdt = __shfl(rden[t0 & 3], (t0 >> 2) * 16);
        const int addr = (((lane >> 1) ^ (t0 & 7)) << 3) + (lane & 1) * 4;
        s16x4 q = *(const s16x4*)&lds_w[wv][t0][addr];
        f32x4 o;
        o[0] = bf2f((unsigned short)q[0]) * rdt;
        o[1] = bf2f((unsigned short)q[1]) * rdt;
        o[2] = bf2f((unsigned short)q[2]) * rdt;
        o[3] = bf2f((unsigned short)q[3]) * rdt;
        *(f32x4*)&wout[(size_t)t0 * NCELLS + lane * 4] = o;
    }

    // ---- Phase 5: blended = (e' @ proto) * rden; B-fragments direct from global ----
    bf16x8 aw[8];
    #pragma unroll
    for (int ks = 0; ks < 8; ++ks)
        aw[ks] = *(const bf16x8*)&lds_w[wv][r][((ks * 4 + g) ^ (r & 7)) << 3];

    float* bout = out_blend + (size_t)tb * DIM;
    #pragma unroll 1
    for (int dt = 0; dt < 32; ++dt) {
        const bf16x8* bT = (const bf16x8*)protoB + (size_t)dt * 8 * 64 + lo;
        f32x4 acc = {0.f, 0.f, 0.f, 0.f};
        #pragma unroll
        for (int s = 0; s < 8; ++s)
            acc = __builtin_amdgcn_mfma_f32_16x16x32_bf16(aw[s], bT[s * 64], acc, 0, 0, 0);
        #pragma unroll
        for (int j = 0; j < 4; ++j)
            bout[(size_t)(g * 4 + j) * DIM + dt * 16 + r] = acc[j] * rden[j];
    }
}

// ---------------- launch ----------------
extern "C" void kernel_launch(void* const* d_in, const int* in_sizes, int n_in,
                              void* d_out, int out_size, void* d_ws, size_t ws_size,
                              hipStream_t stream) {
    const float* x           = (const float*)d_in[0];
    const float* proto       = (const float*)d_in[1];
    const float* grid        = (const float*)d_in[2];
    const float* temp_raw    = (const float*)d_in[3];
    const float* gate_logits = (const float*)d_in[4];

    float* out       = (float*)d_out;
    float* out_blend = out;                          // [N][512]
    float* out_w     = out + (size_t)NTOK * DIM;     // [N][256]

    char* ws = (char*)d_ws;
    unsigned short* pcombB = (unsigned short*)(ws);            // 524288 B
    unsigned short* protoB = (unsigned short*)(ws + 524288);   // 262144 B
    float* pp   = (float*)(ws + 786432);
    float* gg   = (float*)(ws + 787456);
    float* gate = (float*)(ws + 788480);
    float* invT = (float*)(ws + 789504);

    prep_kernel<<<dim3(NCELLS), dim3(256), 0, stream>>>(
        proto, grid, temp_raw, gate_logits, pcombB, protoB, pp, gg, gate, invT);
    som_main<<<dim3(NTOK / 64), dim3(256), 0, stream>>>(
        x, pcombB, protoB, pp, gg, gate, invT, out_blend, out_w);
}